// Round 6
// baseline (401.673 us; speedup 1.0000x reference)
//
#include <hip/hip_runtime.h>
#include <hip/hip_bf16.h>

// Problem constants
#define CC 768
#define MM 32768                // pixels (8*64*64)
#define NQKV 2304               // 3*CC
#define SCALE_ 0.125f           // 64^-0.5

typedef __bf16 bf16x8 __attribute__((ext_vector_type(8)));
typedef float f32x4 __attribute__((ext_vector_type(4)));
typedef unsigned short ushort8_t __attribute__((ext_vector_type(8)));

static __device__ __forceinline__ float bf2f(unsigned short u) {
  return __uint_as_float(((unsigned int)u) << 16);
}
static __device__ __forceinline__ unsigned short f2bf(float f) {
  __hip_bfloat16 t = __float2bfloat16(f);
  return __builtin_bit_cast(unsigned short, t);
}

#define FENCE() asm volatile("" ::: "memory")
#define BAR() do { FENCE(); __builtin_amdgcn_s_barrier(); FENCE(); } while (0)
#define GLDS(src, dst) __builtin_amdgcn_global_load_lds( \
    (const __attribute__((address_space(1))) void*)(src), \
    (__attribute__((address_space(3))) void*)(dst), 16, 0, 0)

// ---------------------------------------------------------------------------
// f32 -> bf16 convert (vectorized float4 -> 4x bf16)
// ---------------------------------------------------------------------------
__global__ void cvt_kernel(const float* __restrict__ in,
                           __hip_bfloat16* __restrict__ out, int n4) {
  int i = blockIdx.x * blockDim.x + threadIdx.x;
  if (i >= n4) return;
  float4 v = reinterpret_cast<const float4*>(in)[i];
  ushort4 o;
  o.x = f2bf(v.x); o.y = f2bf(v.y); o.z = f2bf(v.z); o.w = f2bf(v.w);
  reinterpret_cast<ushort4*>(out)[i] = o;
}

// ---------------------------------------------------------------------------
// 256x256 8-phase bf16 GEMM (T3+T4+T2+T5): D = A[M][K] * Bw[N][K]^T.
// BK=64 (2 K-tiles per 8-phase iteration), 8 waves (2M x 4N), 512 threads,
// LDS = 2 slots x (A 256x64 + B 256x64) bf16 = 128 KiB, 1 block/CU.
// Per phase: {ds_read quadrant frags | stage 1 half-tile} -> barrier ->
//            setprio(1) 16xMFMA setprio(0) -> [vmcnt(2) @ p4/p8] -> barrier.
// Stage schedule (stage-after-last-read; data-kt in brackets):
//   p1 A.hi(s1)[2t+1]  p2 B.lo(s1)[2t+1]  p3 B.hi(s1)[2t+1]
//   p4 A.lo(s0)[2t+2]  p5 A.hi(s0)[2t+2]  p6 B.lo(s0)[2t+2]
//   p7 B.hi(s0)[2t+2]  p8 A.lo(s1)[2t+3]
// vmcnt(2) @p4 retires {prev-p8, p1, p2, p3} = all s1[2t+1] (read p5-p8);
// vmcnt(2) @p8 retires {p4..p7} = all s0[2t+2] (read next p1-p4).
// LDS swizzle (rule #21, R4-verified family): linear LDS dest; source slot
// (l&7)^(l>>3); fragment read slot (ks*4+g)^(row&7) -> 8 bank-quads covered.
// MODE 1: bf16 TRANSPOSED outT[N][M]; MODE 2: f32 out[M][N] + bias.
// ---------------------------------------------------------------------------
template <int MODE>
__global__ __launch_bounds__(512, 2) void gemm256_kernel(
    const __hip_bfloat16* __restrict__ A,
    const __hip_bfloat16* __restrict__ Bw,
    void* __restrict__ outp,
    const float* __restrict__ bias,
    int M, int N, int K) {
  __shared__ __hip_bfloat16 lA[2][256 * 64];
  __shared__ __hip_bfloat16 lB[2][256 * 64];

  const int nBN = N >> 8;
  const int cpx = gridDim.x >> 3;                 // grid % 8 == 0
  const int bid = ((int)blockIdx.x & 7) * cpx + ((int)blockIdx.x >> 3);
  const int bm = bid / nBN;
  const int bn = bid % nBN;
  const int tid = threadIdx.x;
  const int lane = tid & 63;
  const int wv = tid >> 6;                        // 0..7
  const int wr = wv >> 2;                         // M-wave: rows wr*128
  const int wn = wv & 3;                          // N-wave: cols wn*64

  const size_t Abase = (size_t)(bm * 256) * K;
  const size_t Bbase = (size_t)(bn * 256) * K;

  // staging decomposition: lane -> (row-in-8-group, swizzled source slot)
  const int srow8 = lane >> 3;
  const int sslot = (lane & 7) ^ srow8;

  // fragment decomposition
  const int fr = lane & 15;
  const int g = lane >> 4;
  const int sw = lane & 7;                        // row&7 for all frag rows

  f32x4 acc[8][4] = {};

  auto stageA = [&](int slot, int half, int kt) {
#pragma unroll
    for (int i = 0; i < 2; ++i) {
      const int rb = half * 128 + wv * 16 + i * 8;
      const __hip_bfloat16* src =
          A + Abase + (size_t)(rb + srow8) * K + (kt << 6) + (sslot << 3);
      GLDS(src, &lA[slot][rb << 6]);
    }
  };
  auto stageB = [&](int slot, int half, int kt) {
#pragma unroll
    for (int i = 0; i < 2; ++i) {
      const int rb = half * 128 + wv * 16 + i * 8;
      const __hip_bfloat16* src =
          Bw + Bbase + (size_t)(rb + srow8) * K + (kt << 6) + (sslot << 3);
      GLDS(src, &lB[slot][rb << 6]);
    }
  };
  auto ldA = [&](int slot, int m, int ks) -> bf16x8 {
    const int row = wr * 128 + m * 16 + fr;
    const int s = (ks * 4 + g) ^ sw;
    return *reinterpret_cast<const bf16x8*>(&lA[slot][(row << 6) + (s << 3)]);
  };
  auto ldB = [&](int slot, int n, int ks) -> bf16x8 {
    const int row = wn * 64 + n * 16 + fr;
    const int s = (ks * 4 + g) ^ sw;
    return *reinterpret_cast<const bf16x8*>(&lB[slot][(row << 6) + (s << 3)]);
  };

  const int nit = K >> 7;                         // 6 for K=768

  // prologue: s0 kt=0 (4 half-tiles) + A.lo(s1) kt=1; keep newest 2 in flight
  stageA(0, 0, 0); stageA(0, 1, 0); stageB(0, 0, 0); stageB(0, 1, 0);
  stageA(1, 0, 1);
  asm volatile("s_waitcnt vmcnt(2)" ::: "memory");
  BAR();

  bf16x8 a4[4][2], bA[2][2], bB[2][2];

  for (int t = 0; t < nit; ++t) {
    const int k1 = 2 * t + 1, k2 = 2 * t + 2, k3 = 2 * t + 3;
    const bool more = (t + 1 < nit);

    // -------- phase 1: read A[m0-3]+B[n0-1] s0; stage A.hi(s1,k1); m0-3 x n0-1
#pragma unroll
    for (int m = 0; m < 4; ++m) { a4[m][0] = ldA(0, m, 0); a4[m][1] = ldA(0, m, 1); }
#pragma unroll
    for (int n = 0; n < 2; ++n) { bA[n][0] = ldB(0, n, 0); bA[n][1] = ldB(0, n, 1); }
    stageA(1, 1, k1);
    BAR();
    __builtin_amdgcn_s_setprio(1);
#pragma unroll
    for (int m = 0; m < 4; ++m)
#pragma unroll
      for (int n = 0; n < 2; ++n)
#pragma unroll
        for (int ks = 0; ks < 2; ++ks)
          acc[m][n] = __builtin_amdgcn_mfma_f32_16x16x32_bf16(a4[m][ks], bA[n][ks], acc[m][n], 0, 0, 0);
    __builtin_amdgcn_s_setprio(0);
    BAR();

    // -------- phase 2: read B[n2-3] s0; stage B.lo(s1,k1); m0-3 x n2-3
#pragma unroll
    for (int n = 0; n < 2; ++n) { bB[n][0] = ldB(0, n + 2, 0); bB[n][1] = ldB(0, n + 2, 1); }
    stageB(1, 0, k1);
    BAR();
    __builtin_amdgcn_s_setprio(1);
#pragma unroll
    for (int m = 0; m < 4; ++m)
#pragma unroll
      for (int n = 0; n < 2; ++n)
#pragma unroll
        for (int ks = 0; ks < 2; ++ks)
          acc[m][n + 2] = __builtin_amdgcn_mfma_f32_16x16x32_bf16(a4[m][ks], bB[n][ks], acc[m][n + 2], 0, 0, 0);
    __builtin_amdgcn_s_setprio(0);
    BAR();

    // -------- phase 3: read A[m4-7] s0; stage B.hi(s1,k1); m4-7 x n2-3
#pragma unroll
    for (int m = 0; m < 4; ++m) { a4[m][0] = ldA(0, m + 4, 0); a4[m][1] = ldA(0, m + 4, 1); }
    stageB(1, 1, k1);
    BAR();
    __builtin_amdgcn_s_setprio(1);
#pragma unroll
    for (int m = 0; m < 4; ++m)
#pragma unroll
      for (int n = 0; n < 2; ++n)
#pragma unroll
        for (int ks = 0; ks < 2; ++ks)
          acc[m + 4][n + 2] = __builtin_amdgcn_mfma_f32_16x16x32_bf16(a4[m][ks], bB[n][ks], acc[m + 4][n + 2], 0, 0, 0);
    __builtin_amdgcn_s_setprio(0);
    BAR();

    // -------- phase 4: read B[n0-1] s0; stage A.lo(s0,k2); m4-7 x n0-1; vmcnt
#pragma unroll
    for (int n = 0; n < 2; ++n) { bA[n][0] = ldB(0, n, 0); bA[n][1] = ldB(0, n, 1); }
    if (more) stageA(0, 0, k2);
    BAR();
    __builtin_amdgcn_s_setprio(1);
#pragma unroll
    for (int m = 0; m < 4; ++m)
#pragma unroll
      for (int n = 0; n < 2; ++n)
#pragma unroll
        for (int ks = 0; ks < 2; ++ks)
          acc[m + 4][n] = __builtin_amdgcn_mfma_f32_16x16x32_bf16(a4[m][ks], bA[n][ks], acc[m + 4][n], 0, 0, 0);
    __builtin_amdgcn_s_setprio(0);
    if (more) { asm volatile("s_waitcnt vmcnt(2)" ::: "memory"); }
    else      { asm volatile("s_waitcnt vmcnt(0)" ::: "memory"); }
    BAR();

    // -------- phase 5: read A[m0-3]+B[n0-1] s1; stage A.hi(s0,k2); m0-3 x n0-1
#pragma unroll
    for (int m = 0; m < 4; ++m) { a4[m][0] = ldA(1, m, 0); a4[m][1] = ldA(1, m, 1); }
#pragma unroll
    for (int n = 0; n < 2; ++n) { bA[n][0] = ldB(1, n, 0); bA[n][1] = ldB(1, n, 1); }
    if (more) stageA(0, 1, k2);
    BAR();
    __builtin_amdgcn_s_setprio(1);
#pragma unroll
    for (int m = 0; m < 4; ++m)
#pragma unroll
      for (int n = 0; n < 2; ++n)
#pragma unroll
        for (int ks = 0; ks < 2; ++ks)
          acc[m][n] = __builtin_amdgcn_mfma_f32_16x16x32_bf16(a4[m][ks], bA[n][ks], acc[m][n], 0, 0, 0);
    __builtin_amdgcn_s_setprio(0);
    BAR();

    // -------- phase 6: read B[n2-3] s1; stage B.lo(s0,k2); m0-3 x n2-3
#pragma unroll
    for (int n = 0; n < 2; ++n) { bB[n][0] = ldB(1, n + 2, 0); bB[n][1] = ldB(1, n + 2, 1); }
    if (more) stageB(0, 0, k2);
    BAR();
    __builtin_amdgcn_s_setprio(1);
#pragma unroll
    for (int m = 0; m < 4; ++m)
#pragma unroll
      for (int n = 0; n < 2; ++n)
#pragma unroll
        for (int ks = 0; ks < 2; ++ks)
          acc[m][n + 2] = __builtin_amdgcn_mfma_f32_16x16x32_bf16(a4[m][ks], bB[n][ks], acc[m][n + 2], 0, 0, 0);
    __builtin_amdgcn_s_setprio(0);
    BAR();

    // -------- phase 7: read A[m4-7] s1; stage B.hi(s0,k2); m4-7 x n2-3
#pragma unroll
    for (int m = 0; m < 4; ++m) { a4[m][0] = ldA(1, m + 4, 0); a4[m][1] = ldA(1, m + 4, 1); }
    if (more) stageB(0, 1, k2);
    BAR();
    __builtin_amdgcn_s_setprio(1);
#pragma unroll
    for (int m = 0; m < 4; ++m)
#pragma unroll
      for (int n = 0; n < 2; ++n)
#pragma unroll
        for (int ks = 0; ks < 2; ++ks)
          acc[m + 4][n + 2] = __builtin_amdgcn_mfma_f32_16x16x32_bf16(a4[m][ks], bB[n][ks], acc[m + 4][n + 2], 0, 0, 0);
    __builtin_amdgcn_s_setprio(0);
    BAR();

    // -------- phase 8: read B[n0-1] s1; stage A.lo(s1,k3); m4-7 x n0-1; vmcnt
#pragma unroll
    for (int n = 0; n < 2; ++n) { bA[n][0] = ldB(1, n, 0); bA[n][1] = ldB(1, n, 1); }
    if (more) stageA(1, 0, k3);
    BAR();
    __builtin_amdgcn_s_setprio(1);
#pragma unroll
    for (int m = 0; m < 4; ++m)
#pragma unroll
      for (int n = 0; n < 2; ++n)
#pragma unroll
        for (int ks = 0; ks < 2; ++ks)
          acc[m + 4][n] = __builtin_amdgcn_mfma_f32_16x16x32_bf16(a4[m][ks], bA[n][ks], acc[m + 4][n], 0, 0, 0);
    __builtin_amdgcn_s_setprio(0);
    if (more) { asm volatile("s_waitcnt vmcnt(2)" ::: "memory"); }
    BAR();
  }

  // epilogue: C/D layout col = lane&15, row = (lane>>4)*4 + r   [m89]
  const int r0 = (lane >> 4) * 4;
  const int cc_ = lane & 15;
#pragma unroll
  for (int m = 0; m < 8; ++m) {
#pragma unroll
    for (int n = 0; n < 4; ++n) {
      const int grow = bm * 256 + wr * 128 + m * 16 + r0;
      const int gcol = bn * 256 + wn * 64 + n * 16 + cc_;
      if (MODE == 1) {
        __hip_bfloat16* outT = (__hip_bfloat16*)outp;
        ushort4 pk;
        pk.x = f2bf(acc[m][n][0]);
        pk.y = f2bf(acc[m][n][1]);
        pk.z = f2bf(acc[m][n][2]);
        pk.w = f2bf(acc[m][n][3]);
        *reinterpret_cast<ushort4*>(outT + (size_t)gcol * M + grow) = pk;
      } else {
        float* outF = (float*)outp;
        const float bv = bias ? bias[gcol] : 0.f;
#pragma unroll
        for (int r = 0; r < 4; ++r)
          outF[(size_t)(grow + r) * N + gcol] = acc[m][n][r] + bv;
      }
    }
  }
}

// ---------------------------------------------------------------------------
// Dilated local attention v3 (unchanged from R5): thread = (pixel, head, half).
// ---------------------------------------------------------------------------
__global__ __launch_bounds__(256) void attn_kernel(
    const unsigned short* __restrict__ qkvT,
    const unsigned short* __restrict__ xres,
    unsigned short* __restrict__ y) {
  const int hh = blockIdx.x >> 7;              // 0..23 (uniform per block)
  const int head = hh >> 1;
  const int half = hh & 1;
  const int p = ((blockIdx.x & 127) << 8) + threadIdx.x;  // pixel
  const int h = (p >> 6) & 63;
  const int w = p & 63;
  const int grp = head >> 2;
  const int dil = grp + 1;                     // DILATIONS = (1,2,3)
  const int chq = grp * 256 + (head & 3) * 64;

  int voff[9];
  bool valid[9];
#pragma unroll
  for (int t = 0; t < 9; ++t) {
    const int di = t / 3 - 1, dj = t % 3 - 1;
    valid[t] = ((unsigned)(h + di * dil) < 64u) && ((unsigned)(w + dj * dil) < 64u);
    voff[t] = p + (di * 64 + dj) * dil + 256;  // +256 bias keeps index >= 0
  }
  const int voffq = p + 256;

  const unsigned short* qb = qkvT + (size_t)chq * MM - 256;
  const unsigned short* kb = qkvT + (size_t)(768 + chq) * MM - 256;

  float l[9] = {};
#pragma unroll 1
  for (int cb = 0; cb < 16; ++cb) {
    unsigned short qv[4];
    unsigned short kv[4][9];
#pragma unroll
    for (int i = 0; i < 4; ++i) qv[i] = qb[voffq + i * MM];
#pragma unroll
    for (int i = 0; i < 4; ++i)
#pragma unroll
      for (int t = 0; t < 9; ++t) kv[i][t] = kb[voff[t] + i * MM];
#pragma unroll
    for (int i = 0; i < 4; ++i) {
      const float qf = bf2f(qv[i]);
#pragma unroll
      for (int t = 0; t < 9; ++t)
        l[t] = fmaf(qf, bf2f(kv[i][t]), l[t]);
    }
    qb += 4 * MM;
    kb += 4 * MM;
  }

#pragma unroll
  for (int t = 0; t < 9; ++t) l[t] = valid[t] ? l[t] * SCALE_ : 0.f;
  float mx = l[0];
#pragma unroll
  for (int t = 1; t < 9; ++t) mx = fmaxf(mx, l[t]);
  float den = 0.f;
#pragma unroll
  for (int t = 0; t < 9; ++t) {
    const float e = __expf(l[t] - mx);
    den += e;                                  // invalid taps count in denom
    l[t] = valid[t] ? e : 0.f;                 // but contribute 0 to numerator
  }
  const float inv = 1.f / den;
#pragma unroll
  for (int t = 0; t < 9; ++t) l[t] *= inv;

  const int cho = chq + half * 32;
  const unsigned short* vb = qkvT + (size_t)(1536 + cho) * MM - 256;
  float vout[32];
#pragma unroll 1
  for (int cb = 0; cb < 8; ++cb) {
    unsigned short vv[4][9];
#pragma unroll
    for (int i = 0; i < 4; ++i)
#pragma unroll
      for (int t = 0; t < 9; ++t) vv[i][t] = vb[voff[t] + i * MM];
#pragma unroll
    for (int i = 0; i < 4; ++i) {
      float acc = 0.f;
#pragma unroll
      for (int t = 0; t < 9; ++t)
        acc = fmaf(l[t], bf2f(vv[i][t]), acc);
      vout[cb * 4 + i] = acc;
    }
    vb += 4 * MM;
  }

  const ushort8_t* xr = reinterpret_cast<const ushort8_t*>(xres + (size_t)p * CC + cho);
  ushort8_t* yr = reinterpret_cast<ushort8_t*>(y + (size_t)p * CC + cho);
#pragma unroll
  for (int k = 0; k < 4; ++k) {
    const ushort8_t xa = xr[k];
    ushort8_t o;
#pragma unroll
    for (int j = 0; j < 8; ++j)
      o[j] = f2bf(vout[8 * k + j] + bf2f(xa[j]));
    yr[k] = o;
  }
}

// ---------------------------------------------------------------------------
// launch
// ---------------------------------------------------------------------------
extern "C" void kernel_launch(void* const* d_in, const int* in_sizes, int n_in,
                              void* d_out, int out_size, void* d_ws, size_t ws_size,
                              hipStream_t stream) {
  const float* x = (const float*)d_in[0];
  const float* qkv_w = (const float*)d_in[1];
  const float* proj_w = (const float*)d_in[2];
  const float* proj_b = (const float*)d_in[3];
  float* out = (float*)d_out;

  char* ws = (char*)d_ws;
  // ws layout (bytes), total 206,045,184:
  //   [0, 50331648)            xb [M][768] bf16  -> reused as y [M][768] bf16
  //   [50331648, 201326592)    qkvT [2304][M] bf16
  //   [201326592, 204865536)   wqkvb [2304][768] bf16 (absorbs OOB tap reads)
  //   [204865536, 206045184)   wprojb [768][768] bf16
  __hip_bfloat16* xb = (__hip_bfloat16*)(ws);
  __hip_bfloat16* qkvT = (__hip_bfloat16*)(ws + 50331648);
  __hip_bfloat16* wqkvb = (__hip_bfloat16*)(ws + 201326592);
  __hip_bfloat16* wprojb = (__hip_bfloat16*)(ws + 204865536);
  __hip_bfloat16* ybuf = xb;                   // y overwrites xb (per-thread
                                               // read-then-write, exclusive)

  cvt_kernel<<<(MM * CC / 4 + 255) / 256, 256, 0, stream>>>(x, xb, MM * CC / 4);
  cvt_kernel<<<(NQKV * CC / 4 + 255) / 256, 256, 0, stream>>>(qkv_w, wqkvb, NQKV * CC / 4);
  cvt_kernel<<<(CC * CC / 4 + 255) / 256, 256, 0, stream>>>(proj_w, wprojb, CC * CC / 4);

  // qkv GEMM -> channel-major qkvT [2304][M]   (grid 1152 % 8 == 0)
  gemm256_kernel<1><<<(MM / 256) * (NQKV / 256), 512, 0, stream>>>(
      xb, wqkvb, (void*)qkvT, nullptr, MM, NQKV, CC);

  // attention + residual -> y [M][768] bf16 (24 head-halves x 128 pixel-blocks)
  attn_kernel<<<24 * 128, 256, 0, stream>>>(
      (const unsigned short*)qkvT, (const unsigned short*)xb,
      (unsigned short*)ybuf);

  // proj GEMM -> f32 out [M][768] + bias      (grid 384 % 8 == 0)
  gemm256_kernel<2><<<(MM / 256) * (CC / 256), 512, 0, stream>>>(
      ybuf, wprojb, (void*)out, proj_b, MM, CC, CC);
}